// Round 2
// baseline (225.990 us; speedup 1.0000x reference)
//
#include <hip/hip_runtime.h>

// out[s,b,d] = x[s,b,d] + (2047.5 - s), shape (4096, 4, 2048) fp32.
// Pure streaming, zero reuse: 268 MB total traffic.
//
// R1 findings (rocprof): the 217.6 us metric = 2 harness poison-fills
// (79.7 us each, 512 MB @ 6.7 TB/s, fixed cost ~159 us) + kernel ~58.2 us.
// Kernel BW = 268 MB / 58.2 us = 4.6 TB/s vs 6.3 TB/s plain-copy ceiling
// (m13) and 6.7 TB/s seen by the non-NT fills in this very profile.
//
// R1 change: drop the nontemporal hints (the only structural difference
// vs the 6.3+ TB/s references). NT r+w stream measured 4.6 TB/s; plain
// r+w copy measures 6.3 TB/s on this box. Also: input was just poisoned
// by the fill, so part of it is L3-resident — allocating reads can
// harvest those hits; zero reuse means allocation has no downside.
// Predicted: kernel 58 -> ~43-47 us, metric ~203-207 us.
//
// Layout: 4 float4s per thread, stride-256 interleave (perfect
// coalescing: each wave reads 4x contiguous 1KB segments).
// B*D = 8192 floats per s-row = 2048 float4s => s = i4 >> 11.

typedef float fvec4 __attribute__((ext_vector_type(4)));

__global__ __launch_bounds__(256) void rpe_kernel(const fvec4* __restrict__ x,
                                                  fvec4* __restrict__ out) {
    int base = blockIdx.x * 1024 + threadIdx.x;

    fvec4 v[4];
    int idx[4];
    #pragma unroll
    for (int k = 0; k < 4; ++k) {
        idx[k] = base + k * 256;
        v[k] = x[idx[k]];
    }
    #pragma unroll
    for (int k = 0; k < 4; ++k) {
        float bias = 2047.5f - (float)(idx[k] >> 11);
        v[k] += bias;   // ext_vector: scalar broadcast add
        out[idx[k]] = v[k];
    }
}

extern "C" void kernel_launch(void* const* d_in, const int* in_sizes, int n_in,
                              void* d_out, int out_size, void* d_ws, size_t ws_size,
                              hipStream_t stream) {
    const fvec4* x = (const fvec4*)d_in[0];
    fvec4* out = (fvec4*)d_out;
    int n4 = in_sizes[0] / 4;                 // 8,388,608, divisible by 1024
    int blocks = n4 / 1024;                   // 8192 blocks x 256 threads x 4 float4
    rpe_kernel<<<blocks, 256, 0, stream>>>(x, out);
}

// Round 3
// 219.372 us; speedup vs baseline: 1.0302x; 1.0302x over previous
//
#include <hip/hip_runtime.h>

// out[s,b,d] = x[s,b,d] + (2047.5 - s), shape (4096, 4, 2048) fp32.
// Pure streaming, zero reuse: 268 MB compulsory traffic.
//
// Measured ladder (kernel time inferred as metric - 2 poison fills @ ~80us):
//   NT load + NT store     : 58.5 us (4.6 TB/s)   [R0/R1 baseline]
//   plain load + plain st. : 65.4 us (4.1 TB/s)   [R2 — regression]
//
// R2 post-mortem: harness poison fills (512 MB, plain allocating stores,
// 6.7 TB/s) leave L2/L3 full of DIRTY poison lines. Plain loads allocate
// -> evict dirty poison -> wasted HBM writebacks (hidden extra traffic).
// Plain stores, by contrast, overwrite resident dirty poison IN PLACE
// (poison never reaches HBM; final data writes back once, lazily) — the
// fills themselves prove plain write streams run at 6.7 TB/s.
//
// R3 change: the untested quadrant — NT LOAD (don't disturb the dirty
// cache) + PLAIN STORE (harvest in-place overwrite). Predict kernel
// ~45-52 us, metric ~206-213. If unchanged vs 217.6, the residual gap is
// read<->write bus turnaround and ~4.6 TB/s is the mixed-stream ceiling.
//
// Layout: 4 float4s per thread, stride-256 interleave (each wave: 4x
// contiguous 1KB bursts; block covers 16 KB contiguous).
// B*D = 8192 floats per s-row = 2048 float4s => s = i4 >> 11.

typedef float fvec4 __attribute__((ext_vector_type(4)));

__global__ __launch_bounds__(256) void rpe_kernel(const fvec4* __restrict__ x,
                                                  fvec4* __restrict__ out) {
    int base = blockIdx.x * 1024 + threadIdx.x;

    fvec4 v[4];
    int idx[4];
    #pragma unroll
    for (int k = 0; k < 4; ++k) {
        idx[k] = base + k * 256;
        v[k] = __builtin_nontemporal_load(&x[idx[k]]);
    }
    #pragma unroll
    for (int k = 0; k < 4; ++k) {
        float bias = 2047.5f - (float)(idx[k] >> 11);
        v[k] += bias;   // ext_vector: scalar broadcast add
        out[idx[k]] = v[k];        // plain allocating store
    }
}

extern "C" void kernel_launch(void* const* d_in, const int* in_sizes, int n_in,
                              void* d_out, int out_size, void* d_ws, size_t ws_size,
                              hipStream_t stream) {
    const fvec4* x = (const fvec4*)d_in[0];
    fvec4* out = (fvec4*)d_out;
    int n4 = in_sizes[0] / 4;                 // 8,388,608, divisible by 1024
    int blocks = n4 / 1024;                   // 8192 blocks x 256 threads x 4 float4
    rpe_kernel<<<blocks, 256, 0, stream>>>(x, out);
}